// Round 7
// baseline (805.953 us; speedup 1.0000x reference)
//
#include <hip/hip_runtime.h>

#define EPS 1e-5f

typedef __attribute__((ext_vector_type(8))) short short8;
typedef __attribute__((ext_vector_type(4))) float float4v;

__device__ __forceinline__ unsigned short f2bf(float x) {
  unsigned int u = __builtin_bit_cast(unsigned int, x);
  u += 0x7fffu + ((u >> 16) & 1u);   // RNE to bf16
  return (unsigned short)(u >> 16);
}
__device__ __forceinline__ float bf2f(unsigned short h) {
  unsigned int u = ((unsigned int)h) << 16;
  return __builtin_bit_cast(float, u);
}

// ---------------- Kernel 1: LayerNorm (+ zero `inner` for attnv atomics) ----------------
__global__ __launch_bounds__(256) void ln_kernel(
    const float* __restrict__ x, const float* __restrict__ gamma,
    const float* __restrict__ beta, float* __restrict__ xn,
    float* __restrict__ inner) {
  {
    const int zi = blockIdx.x * 1024 + threadIdx.x * 4;
    float4 z; z.x = 0.f; z.y = 0.f; z.z = 0.f; z.w = 0.f;
    *(float4*)(inner + zi) = z;
  }
  const int row = blockIdx.x * 4 + (threadIdx.x >> 6);
  const int lane = threadIdx.x & 63;
  const float2 v = ((const float2*)(x + (size_t)row * 128))[lane];
  float s = v.x + v.y;
#pragma unroll
  for (int off = 1; off < 64; off <<= 1) s += __shfl_xor(s, off);
  const float mu = s * (1.f / 128.f);
  const float dx = v.x - mu, dy = v.y - mu;
  float qv = dx * dx + dy * dy;
#pragma unroll
  for (int off = 1; off < 64; off <<= 1) qv += __shfl_xor(qv, off);
  const float rstd = 1.f / sqrtf(qv * (1.f / 128.f) + EPS);
  const float2 g = ((const float2*)gamma)[lane];
  const float2 be = ((const float2*)beta)[lane];
  float2 o;
  o.x = dx * rstd * g.x + be.x;
  o.y = dy * rstd * g.y + be.y;
  ((float2*)(xn + (size_t)row * 128))[lane] = o;
}

// ---------------- Kernel 2: qk = xn @ Wqk  [4160,128]x[128,512] ----------------
__global__ __launch_bounds__(256) void qk_kernel(
    const float* __restrict__ xn, const float* __restrict__ Wqk,
    float* __restrict__ qk) {
  __shared__ float xsx[32][130];
  __shared__ float wsx[128][68];
  const int t = threadIdx.x;
  const int r0 = blockIdx.x * 32, c0 = blockIdx.y * 64;
  for (int i = t; i < 32 * 32; i += 256) {
    int r = i >> 5, c = (i & 31) << 2;
    float4 v = *(const float4*)(xn + (size_t)(r0 + r) * 128 + c);
    float* dst = &xsx[r][c];
    dst[0] = v.x; dst[1] = v.y; dst[2] = v.z; dst[3] = v.w;
  }
  for (int i = t; i < 128 * 16; i += 256) {
    int k = i >> 4, c = (i & 15) << 2;
    *(float4*)&wsx[k][c] = *(const float4*)(Wqk + (size_t)k * 512 + c0 + c);
  }
  __syncthreads();
  const int rr = (t >> 4) * 2, cc = (t & 15) * 4;
  float acc[2][4] = {{0.f, 0.f, 0.f, 0.f}, {0.f, 0.f, 0.f, 0.f}};
  for (int k = 0; k < 128; k++) {
    float4 wv4 = *(const float4*)&wsx[k][cc];
    float x0 = xsx[rr][k], x1 = xsx[rr + 1][k];
    acc[0][0] += x0 * wv4.x; acc[0][1] += x0 * wv4.y;
    acc[0][2] += x0 * wv4.z; acc[0][3] += x0 * wv4.w;
    acc[1][0] += x1 * wv4.x; acc[1][1] += x1 * wv4.y;
    acc[1][2] += x1 * wv4.z; acc[1][3] += x1 * wv4.w;
  }
#pragma unroll
  for (int r = 0; r < 2; r++) {
    float4 o;
    o.x = acc[r][0]; o.y = acc[r][1]; o.z = acc[r][2]; o.w = acc[r][3];
    *(float4*)(qk + (size_t)(r0 + rr + r) * 512 + c0 + cc) = o;
  }
}

// ---------------- Kernel 3: dots + softmax ----------------
__global__ __launch_bounds__(256) void softmax_kernel(
    const float* __restrict__ qk, float* __restrict__ attn) {
  const int b = blockIdx.x >> 3, h = blockIdx.x & 7;
  __shared__ float qs[65][33];
  __shared__ float ks[65][33];
  __shared__ float dotsS[65][66];
  __shared__ float rsum[65];
  const int t = threadIdx.x;
  for (int i = t; i < 65 * 32; i += 256) {
    int n = i >> 5, d = i & 31;
    size_t base = ((size_t)b * 65 + n) * 512 + h * 32 + d;
    qs[n][d] = qk[base];
    ks[n][d] = qk[base + 256];
  }
  __syncthreads();
  const float scale = 0.17677669529663687f;  // 1/sqrt(32)
  for (int i = t; i < 65 * 65; i += 256) {
    int n = i / 65, mm = i - n * 65;
    float s = 0.f;
#pragma unroll
    for (int d = 0; d < 32; d++) s += qs[n][d] * ks[mm][d];
    dotsS[n][mm] = s * scale;
  }
  __syncthreads();
  if (t < 65) {
    float mx = -1e30f;
    for (int mm = 0; mm < 65; mm++) mx = fmaxf(mx, dotsS[t][mm]);
    float sum = 0.f;
    for (int mm = 0; mm < 65; mm++) {
      float e = __expf(dotsS[t][mm] - mx);
      dotsS[t][mm] = e;
      sum += e;
    }
    rsum[t] = 1.f / sum;
  }
  __syncthreads();
  const size_t obase = ((size_t)b * 8 + h) * 65 * 65;
  for (int i = t; i < 65 * 65; i += 256) {
    int n = i / 65;
    attn[obase + i] = dotsS[n][i - n * 65] * rsum[n];
  }
}

// ---------------- Kernel 4: big contraction, all-heads-per-block (contiguous Wv stream) ----
// inner[b,n,e] += sum_{m in chunk} attn[b, e>>5, n, m] * sum_d xn[b,n,d]*Wv[n,m,d,e]
// grid (65,16) = (nq, m-chunk); 512 thr / 8 waves = 2 row-groups x 4 e-col-groups.
// Per m: Wv[nq,m] = 128KB read CONTIGUOUSLY in aggregate (256B per wave-instr),
// converted to bf16 LDS [e=256][k=128] (chunk-XOR swizzle), double-buffered.
// 1 block/CU (141KB LDS); pipeline self-paces against HBM BW.
__global__ __launch_bounds__(512, 2) void attnv_kernel(
    const float* __restrict__ xn, const float* __restrict__ attn,
    const float* __restrict__ Wv, float* __restrict__ inner) {
  __shared__ __align__(16) char sbuf[131072];  // xs[64][130] f32 OR wv[2][256][128] bf16
  __shared__ float attnL[5 * 8 * 64];          // [mloc][h][b]
  float* xs = (float*)sbuf;
  unsigned short* wvb = (unsigned short*)sbuf;

  const int nq = blockIdx.x;
  const int mc = blockIdx.y;
  const int ms = (mc * 65) >> 4;
  const int cnt = (((mc + 1) * 65) >> 4) - ms;  // 4 (x15) or 5 (last)

  const int t = threadIdx.x;
  const int lane = t & 63;
  const int w = t >> 6;
  const int er = lane & 15, q = lane >> 4;
  const int rg = w & 1, cg = w >> 1;  // rows rg*32..+31, e-cols cg*64..+63

  // Wv staging: thread owns e-column eS, d-range dS0..dS0+63 (64 loads @ 1KB stride;
  // per wave-instruction: 64 consecutive e at one d = 256B contiguous)
  const int eS = t & 255;
  const int dS0 = (t >> 8) << 6;
  const float* wq = Wv + ((size_t)nq * 65 + ms) * 32768 + (size_t)dS0 * 256 + eS;

  float stg[64];

#define ISSUE(mm) do {                                                        \
    const float* p_ = wq + (size_t)(mm) * 32768;                              \
    _Pragma("unroll")                                                         \
    for (int i_ = 0; i_ < 64; i_++)                                           \
      stg[i_] = __builtin_nontemporal_load(p_ + (size_t)i_ * 256);            \
  } while (0)

  // elem (e, d): chunk c = d>>3 stored at row e, position (c ^ (e&15)), slot d&7
#define CONVWRITE(buf) do {                                                   \
    unsigned short* wb_ = wvb + (size_t)(buf) * 32768 + eS * 128;             \
    const int cb_ = (t >> 8) << 3;                                            \
    _Pragma("unroll")                                                         \
    for (int jj_ = 0; jj_ < 8; jj_++) {                                       \
      short8 pk_;                                                             \
      _Pragma("unroll")                                                       \
      for (int j_ = 0; j_ < 8; j_++) pk_[j_] = (short)f2bf(stg[jj_ * 8 + j_]);\
      *(short8*)&wb_[((cb_ + jj_) ^ (eS & 15)) << 3] = pk_;                   \
    }                                                                         \
  } while (0)

  ISSUE(0);  // m=ms loads in flight across all staging

  // attn chunk -> attnL[mloc][h][b]  (mloc fastest in i for partial coalescing)
  const int tot = cnt << 9;  // 64*8*cnt
  for (int i = t; i < tot; i += 512) {
    int mloc = i % cnt;
    int rest = i / cnt;
    int h = rest & 7;
    int b = rest >> 3;
    attnL[(mloc * 8 + h) * 64 + b] =
        attn[(((size_t)(b * 8 + h) * 65) + nq) * 65 + ms + mloc];
  }
  // xn rows -> xs (stride 130)
  for (int i = t; i < 64 * 32; i += 512) {
    int b = i >> 5, c = (i & 31) << 2;
    float4 v = *(const float4*)(xn + ((size_t)b * 65 + nq) * 128 + c);
    float* dst = xs + b * 130 + c;
    dst[0] = v.x; dst[1] = v.y; dst[2] = v.z; dst[3] = v.w;
  }
  __syncthreads();

  // A fragments (hi/lo split): rows rg*32 + rt*16 + er, k = s*32 + q*8 + j
  short8 ah[2][4], al[2][4];
#pragma unroll
  for (int rt = 0; rt < 2; rt++) {
    const int arow = rg * 32 + rt * 16 + er;
#pragma unroll
    for (int s = 0; s < 4; s++) {
#pragma unroll
      for (int j = 0; j < 8; j++) {
        float xv = xs[arow * 130 + s * 32 + q * 8 + j];
        unsigned short hi = f2bf(xv);
        ah[rt][s][j] = (short)hi;
        al[rt][s][j] = (short)f2bf(xv - bf2f(hi));
      }
    }
  }
  __syncthreads();  // xs dead; sbuf becomes Wv double buffer

  CONVWRITE(0);
  __syncthreads();

  float4v acc[2][4];
#pragma unroll
  for (int rt = 0; rt < 2; rt++)
#pragma unroll
    for (int ct = 0; ct < 4; ct++)
      acc[rt][ct] = (float4v){0.f, 0.f, 0.f, 0.f};

  for (int i = 0; i < cnt; i++) {
    if (i + 1 < cnt) ISSUE(i + 1);  // next-m loads hide under MFMA+DS phase
    const unsigned short* wb = wvb + (size_t)(i & 1) * 32768;
    float4v P[2][4];
#pragma unroll
    for (int rt = 0; rt < 2; rt++)
#pragma unroll
      for (int ct = 0; ct < 4; ct++)
        P[rt][ct] = (float4v){0.f, 0.f, 0.f, 0.f};
    __builtin_amdgcn_s_setprio(1);
#pragma unroll
    for (int s = 0; s < 4; s++) {
      const int kc = 4 * s + q;
#pragma unroll
      for (int ct = 0; ct < 4; ct++) {
        // e = cg*64 + ct*16 + er  ->  e&15 == er, swizzle formula unchanged
        short8 bf = *(const short8*)&wb[(cg * 64 + ct * 16 + er) * 128 + ((kc ^ er) << 3)];
        P[0][ct] = __builtin_amdgcn_mfma_f32_16x16x32_bf16(ah[0][s], bf, P[0][ct], 0, 0, 0);
        P[0][ct] = __builtin_amdgcn_mfma_f32_16x16x32_bf16(al[0][s], bf, P[0][ct], 0, 0, 0);
        P[1][ct] = __builtin_amdgcn_mfma_f32_16x16x32_bf16(ah[1][s], bf, P[1][ct], 0, 0, 0);
        P[1][ct] = __builtin_amdgcn_mfma_f32_16x16x32_bf16(al[1][s], bf, P[1][ct], 0, 0, 0);
      }
    }
    __builtin_amdgcn_s_setprio(0);
    // attn-weight into accumulators: h = cg*2 + (ct>>1); b = rg*32 + rt*16 + q*4 + r
#pragma unroll
    for (int rt = 0; rt < 2; rt++) {
#pragma unroll
      for (int ct = 0; ct < 4; ct++) {
        const int h = cg * 2 + (ct >> 1);
        const float* ap = attnL + (i * 8 + h) * 64 + rg * 32 + rt * 16 + q * 4;
#pragma unroll
        for (int r = 0; r < 4; r++) acc[rt][ct][r] += ap[r] * P[rt][ct][r];
      }
    }
    if (i + 1 < cnt) CONVWRITE((i + 1) & 1);
    __syncthreads();
  }

#undef ISSUE
#undef CONVWRITE

  // epilogue: D layout col=er, row=q*4+r within each 16x16 tile; partial sum over m-chunk
#pragma unroll
  for (int rt = 0; rt < 2; rt++) {
#pragma unroll
    for (int ct = 0; ct < 4; ct++) {
      const int ecol = cg * 64 + ct * 16 + er;
#pragma unroll
      for (int r = 0; r < 4; r++) {
        const int b = rg * 32 + rt * 16 + q * 4 + r;
        atomicAdd(inner + ((size_t)b * 65 + nq) * 256 + ecol, acc[rt][ct][r]);
      }
    }
  }
}

// ---------------- Kernel 5: out = inner @ Wout + bout  [4160,256]x[256,128] ----------------
__global__ __launch_bounds__(256) void outproj_kernel(
    const float* __restrict__ inner, const float* __restrict__ Wout,
    const float* __restrict__ bout, float* __restrict__ out) {
  __shared__ float isx[16][258];
  __shared__ float wsx[64][132];
  const int t = threadIdx.x;
  const int r0 = blockIdx.x * 16;
  for (int i = t; i < 16 * 64; i += 256) {
    int r = i >> 6, c = (i & 63) << 2;
    float4 v = *(const float4*)(inner + (size_t)(r0 + r) * 256 + c);
    float* dst = &isx[r][c];
    dst[0] = v.x; dst[1] = v.y; dst[2] = v.z; dst[3] = v.w;
  }
  const int rr = (t >> 5) * 2, cc = (t & 31) * 4;
  float acc[2][4] = {{0.f, 0.f, 0.f, 0.f}, {0.f, 0.f, 0.f, 0.f}};
  for (int kc = 0; kc < 4; kc++) {
    __syncthreads();
    for (int i = t; i < 64 * 32; i += 256) {
      int k = i >> 5, c = (i & 31) << 2;
      *(float4*)&wsx[k][c] = *(const float4*)(Wout + (size_t)(kc * 64 + k) * 128 + c);
    }
    __syncthreads();
#pragma unroll 8
    for (int k = 0; k < 64; k++) {
      float4 wv4 = *(const float4*)&wsx[k][cc];
      float x0 = isx[rr][kc * 64 + k];
      float x1 = isx[rr + 1][kc * 64 + k];
      acc[0][0] += x0 * wv4.x; acc[0][1] += x0 * wv4.y;
      acc[0][2] += x0 * wv4.z; acc[0][3] += x0 * wv4.w;
      acc[1][0] += x1 * wv4.x; acc[1][1] += x1 * wv4.y;
      acc[1][2] += x1 * wv4.z; acc[1][3] += x1 * wv4.w;
    }
  }
  float4 bb = *(const float4*)(bout + cc);
#pragma unroll
  for (int r = 0; r < 2; r++) {
    float4 o;
    o.x = acc[r][0] + bb.x; o.y = acc[r][1] + bb.y;
    o.z = acc[r][2] + bb.z; o.w = acc[r][3] + bb.w;
    *(float4*)(out + (size_t)(r0 + rr + r) * 128 + cc) = o;
  }
}

extern "C" void kernel_launch(void* const* d_in, const int* in_sizes, int n_in,
                              void* d_out, int out_size, void* d_ws, size_t ws_size,
                              hipStream_t stream) {
  const float* x     = (const float*)d_in[0];
  const float* gamma = (const float*)d_in[1];
  const float* beta  = (const float*)d_in[2];
  const float* Wqk   = (const float*)d_in[3];
  const float* Wv    = (const float*)d_in[4];
  const float* Wout  = (const float*)d_in[5];
  const float* bout  = (const float*)d_in[6];
  float* out = (float*)d_out;
  float* ws  = (float*)d_ws;

  float* xn    = ws;                  // 532,480
  float* qk    = ws + 532480;         // 2,129,920
  float* attn  = ws + 2662400;        // 2,163,200
  float* inner = ws + 4825600;        // 1,064,960   (total 23.6 MB)

  ln_kernel<<<1040, 256, 0, stream>>>(x, gamma, beta, xn, inner);
  qk_kernel<<<dim3(130, 8), 256, 0, stream>>>(xn, Wqk, qk);
  softmax_kernel<<<512, 256, 0, stream>>>(qk, attn);
  attnv_kernel<<<dim3(65, 16), 512, 0, stream>>>(xn, attn, Wv, inner);
  outproj_kernel<<<260, 256, 0, stream>>>(inner, Wout, bout, out);
}